// Round 1
// baseline (1775.913 us; speedup 1.0000x reference)
//
#include <hip/hip_runtime.h>

#define DIMD 512
#define NSEQ 4096
#define BATCH 2
#define NHEADS 8
#define DKH 64

// XOR swizzle for [64][64] fp32 LDS tiles accessed as float4 chunks.
// chunk in [0,16), row in [0,64). Spreads rows across bank groups.
__device__ __forceinline__ int swz(int row, int chunk) {
    return (row << 6) + ((chunk ^ ((row >> 2) & 7)) << 2);
}

// ---------------- fp32 tiled GEMM body: 64x64 tile, 256 thr, 4x4/thread ----------
__device__ __forceinline__ void gemm_body(const float* __restrict__ X,
                                          const float* __restrict__ W,
                                          int m0, int n0, int t,
                                          float (*As)[68], float (*Bs)[64],
                                          float acc[4][4])
{
    const int tx = t & 15, ty = t >> 4;
    for (int k0 = 0; k0 < DIMD; k0 += 16) {
        {   // A tile: 64 rows x 16 k, stored transposed As[k][m]
            const int row = t >> 2;
            const int kc = (t & 3) << 2;
            const float4 a = *reinterpret_cast<const float4*>(
                X + (size_t)(m0 + row) * DIMD + k0 + kc);
            As[kc + 0][row] = a.x;
            As[kc + 1][row] = a.y;
            As[kc + 2][row] = a.z;
            As[kc + 3][row] = a.w;
        }
        {   // B tile: 16 k x 64 n
            const float4 b = *reinterpret_cast<const float4*>(
                W + (size_t)(k0 + ty) * DIMD + n0 + (tx << 2));
            *reinterpret_cast<float4*>(&Bs[ty][tx << 2]) = b;
        }
        __syncthreads();
#pragma unroll
        for (int kk = 0; kk < 16; ++kk) {
            const float4 a4 = *reinterpret_cast<const float4*>(&As[kk][ty << 2]);
            const float4 b4 = *reinterpret_cast<const float4*>(&Bs[kk][tx << 2]);
            const float av[4] = {a4.x, a4.y, a4.z, a4.w};
            const float bv[4] = {b4.x, b4.y, b4.z, b4.w};
#pragma unroll
            for (int i = 0; i < 4; ++i)
#pragma unroll
                for (int j = 0; j < 4; ++j)
                    acc[i][j] = fmaf(av[i], bv[j], acc[i][j]);
        }
        __syncthreads();
    }
}

// ---------------- QKV projection: out = X@W + b, written head-major --------------
__global__ __launch_bounds__(256)
void qkv_proj_kernel(const float* __restrict__ Q, const float* __restrict__ K,
                     const float* __restrict__ V,
                     const float* __restrict__ Wq, const float* __restrict__ bq,
                     const float* __restrict__ Wk, const float* __restrict__ bk,
                     const float* __restrict__ Wv, const float* __restrict__ bv,
                     float* __restrict__ qws, float* __restrict__ kws,
                     float* __restrict__ vws)
{
    __shared__ float As[16][68];
    __shared__ float Bs[16][64];
    const int z = blockIdx.z;
    const float* X    = (z == 0) ? Q  : (z == 1) ? K  : V;
    const float* W    = (z == 0) ? Wq : (z == 1) ? Wk : Wv;
    const float* bias = (z == 0) ? bq : (z == 1) ? bk : bv;
    float* out        = (z == 0) ? qws : (z == 1) ? kws : vws;

    const int t = threadIdx.x;
    const int tx = t & 15, ty = t >> 4;
    const int m0 = blockIdx.x * 64;
    const int n0 = blockIdx.y * 64;

    float acc[4][4] = {};
    gemm_body(X, W, m0, n0, t, As, Bs, acc);

    const int bb = m0 >> 12;      // m0 / NSEQ
    const int h  = blockIdx.y;    // 64-wide n-tile == one head
    float* op = out + (size_t)(bb * NHEADS + h) * NSEQ * DKH;
#pragma unroll
    for (int i = 0; i < 4; ++i) {
        const int m = m0 + (ty << 2) + i;
        const int nrow = m & (NSEQ - 1);
        float4 o;
        o.x = acc[i][0] + bias[n0 + (tx << 2) + 0];
        o.y = acc[i][1] + bias[n0 + (tx << 2) + 1];
        o.z = acc[i][2] + bias[n0 + (tx << 2) + 2];
        o.w = acc[i][3] + bias[n0 + (tx << 2) + 3];
        *reinterpret_cast<float4*>(op + (size_t)nrow * DKH + (tx << 2)) = o;
    }
}

// ---------------- output projection: Y = AO@Wo + bo ------------------------------
__global__ __launch_bounds__(256)
void out_proj_kernel(const float* __restrict__ AO, const float* __restrict__ Wo,
                     const float* __restrict__ bo, float* __restrict__ Y)
{
    __shared__ float As[16][68];
    __shared__ float Bs[16][64];
    const int t = threadIdx.x;
    const int tx = t & 15, ty = t >> 4;
    const int m0 = blockIdx.x * 64;
    const int n0 = blockIdx.y * 64;

    float acc[4][4] = {};
    gemm_body(AO, Wo, m0, n0, t, As, Bs, acc);

#pragma unroll
    for (int i = 0; i < 4; ++i) {
        const int m = m0 + (ty << 2) + i;
        float4 o;
        o.x = acc[i][0] + bo[n0 + (tx << 2) + 0];
        o.y = acc[i][1] + bo[n0 + (tx << 2) + 1];
        o.z = acc[i][2] + bo[n0 + (tx << 2) + 2];
        o.w = acc[i][3] + bo[n0 + (tx << 2) + 3];
        *reinterpret_cast<float4*>(Y + (size_t)m * DIMD + n0 + (tx << 2)) = o;
    }
}

// ---------------- flash attention, fp32, 64q x 64k tiles -------------------------
__global__ __launch_bounds__(256)
void attn_kernel(const float* __restrict__ qws, const float* __restrict__ kws,
                 const float* __restrict__ vws, float* __restrict__ ao)
{
    __shared__ float Qs[64 * 64];
    __shared__ float Ks[64 * 64];
    __shared__ float Vs[64 * 64];
    __shared__ float Ps[64 * 64];

    const int t  = threadIdx.x;
    const int tx = t & 15, ty = t >> 4;
    const int n0 = blockIdx.x * 64;
    const int h  = blockIdx.y;
    const int bb = blockIdx.z;

    const size_t hoff = (size_t)(bb * NHEADS + h) * NSEQ * DKH;
    const float* qh = qws + hoff;
    const float* kh = kws + hoff;
    const float* vh = vws + hoff;

    // stage Q tile once (swizzled)
#pragma unroll
    for (int it = 0; it < 4; ++it) {
        const int row = (t >> 4) + it * 16;
        const int jc  = t & 15;
        const float4 q4 = *reinterpret_cast<const float4*>(
            qh + (size_t)(n0 + row) * DKH + (jc << 2));
        *reinterpret_cast<float4*>(&Qs[swz(row, jc)]) = q4;
    }

    float O[4][4] = {};
    float mrun[4], lrun[4];
#pragma unroll
    for (int a = 0; a < 4; ++a) { mrun[a] = -1e30f; lrun[a] = 0.0f; }

    for (int kt = 0; kt < NSEQ / 64; ++kt) {
        __syncthreads();   // protect Ks/Vs (prev PV) and Ps (prev PV reads)
#pragma unroll
        for (int it = 0; it < 4; ++it) {
            const int row = (t >> 4) + it * 16;
            const int jc  = t & 15;
            const float4 k4 = *reinterpret_cast<const float4*>(
                kh + (size_t)(kt * 64 + row) * DKH + (jc << 2));
            *reinterpret_cast<float4*>(&Ks[swz(row, jc)]) = k4;
            const float4 v4 = *reinterpret_cast<const float4*>(
                vh + (size_t)(kt * 64 + row) * DKH + (jc << 2));
            *reinterpret_cast<float4*>(&Vs[swz(row, jc)]) = v4;
        }
        __syncthreads();

        // scores: thread owns rows ty*4+a, keys tx*4+b
        float s[4][4] = {};
#pragma unroll
        for (int j = 0; j < 16; ++j) {
            float4 q4[4], k4[4];
#pragma unroll
            for (int a = 0; a < 4; ++a)
                q4[a] = *reinterpret_cast<const float4*>(&Qs[swz((ty << 2) + a, j)]);
#pragma unroll
            for (int b = 0; b < 4; ++b)
                k4[b] = *reinterpret_cast<const float4*>(&Ks[swz((tx << 2) + b, j)]);
#pragma unroll
            for (int a = 0; a < 4; ++a)
#pragma unroll
                for (int b = 0; b < 4; ++b)
                    s[a][b] += q4[a].x * k4[b].x + q4[a].y * k4[b].y +
                               q4[a].z * k4[b].z + q4[a].w * k4[b].w;
        }
#pragma unroll
        for (int a = 0; a < 4; ++a)
#pragma unroll
            for (int b = 0; b < 4; ++b)
                s[a][b] *= 0.125f;   // 1/sqrt(64)

        // online softmax: row group = 16 lanes sharing ty (lane bits 0..3)
#pragma unroll
        for (int a = 0; a < 4; ++a) {
            float mloc = fmaxf(fmaxf(s[a][0], s[a][1]), fmaxf(s[a][2], s[a][3]));
#pragma unroll
            for (int mk = 1; mk < 16; mk <<= 1)
                mloc = fmaxf(mloc, __shfl_xor(mloc, mk));
            const float mnew  = fmaxf(mrun[a], mloc);
            const float alpha = __expf(mrun[a] - mnew);
            mrun[a] = mnew;
            const float p0 = __expf(s[a][0] - mnew);
            const float p1 = __expf(s[a][1] - mnew);
            const float p2 = __expf(s[a][2] - mnew);
            const float p3 = __expf(s[a][3] - mnew);
            float psum = p0 + p1 + p2 + p3;
#pragma unroll
            for (int mk = 1; mk < 16; mk <<= 1)
                psum += __shfl_xor(psum, mk);
            lrun[a] = lrun[a] * alpha + psum;
#pragma unroll
            for (int l = 0; l < 4; ++l) O[a][l] *= alpha;
            *reinterpret_cast<float4*>(&Ps[swz((ty << 2) + a, tx)]) =
                make_float4(p0, p1, p2, p3);
        }
        __syncthreads();

        // PV: O[r][d] += sum_k P[r][k] * V[k][d], thread dims d = tx*4..+3
#pragma unroll
        for (int kc = 0; kc < 16; ++kc) {
            float4 p4[4];
#pragma unroll
            for (int a = 0; a < 4; ++a)
                p4[a] = *reinterpret_cast<const float4*>(&Ps[swz((ty << 2) + a, kc)]);
#pragma unroll
            for (int b = 0; b < 4; ++b) {
                const int krow = (kc << 2) + b;
                const float4 v4 = *reinterpret_cast<const float4*>(&Vs[swz(krow, tx)]);
#pragma unroll
                for (int a = 0; a < 4; ++a) {
                    const float pv = (b == 0) ? p4[a].x : (b == 1) ? p4[a].y
                                   : (b == 2) ? p4[a].z : p4[a].w;
                    O[a][0] = fmaf(pv, v4.x, O[a][0]);
                    O[a][1] = fmaf(pv, v4.y, O[a][1]);
                    O[a][2] = fmaf(pv, v4.z, O[a][2]);
                    O[a][3] = fmaf(pv, v4.w, O[a][3]);
                }
            }
        }
    }

    // epilogue: normalize and write to [B][N][D] layout
#pragma unroll
    for (int a = 0; a < 4; ++a) {
        const float inv = 1.0f / lrun[a];
        const int m = n0 + (ty << 2) + a;
        const float4 o = make_float4(O[a][0] * inv, O[a][1] * inv,
                                     O[a][2] * inv, O[a][3] * inv);
        *reinterpret_cast<float4*>(
            ao + ((size_t)bb * NSEQ + m) * DIMD + h * DKH + (tx << 2)) = o;
    }
}

extern "C" void kernel_launch(void* const* d_in, const int* in_sizes, int n_in,
                              void* d_out, int out_size, void* d_ws, size_t ws_size,
                              hipStream_t stream) {
    const float* Q  = (const float*)d_in[0];
    const float* K  = (const float*)d_in[1];
    const float* V  = (const float*)d_in[2];
    const float* Wq = (const float*)d_in[3];
    const float* bq = (const float*)d_in[4];
    const float* Wk = (const float*)d_in[5];
    const float* bk = (const float*)d_in[6];
    const float* Wv = (const float*)d_in[7];
    const float* bv = (const float*)d_in[8];
    const float* Wo = (const float*)d_in[9];
    const float* bo = (const float*)d_in[10];
    float* out = (float*)d_out;
    float* ws  = (float*)d_ws;

    const size_t per = (size_t)BATCH * NSEQ * DIMD;   // 4,194,304 floats
    float* qws = ws;
    float* kws = ws + per;
    float* vws = ws + 2 * per;

    const dim3 gProj(BATCH * NSEQ / 64, DIMD / 64, 3);
    const dim3 gAttn(NSEQ / 64, NHEADS, BATCH);
    const dim3 gOut(BATCH * NSEQ / 64, DIMD / 64, 1);

    qkv_proj_kernel<<<gProj, 256, 0, stream>>>(Q, K, V, Wq, bq, Wk, bk, Wv, bv,
                                               qws, kws, vws);

    if (ws_size >= 4 * per * sizeof(float)) {
        float* ao = ws + 3 * per;
        attn_kernel<<<gAttn, 256, 0, stream>>>(qws, kws, vws, ao);
        out_proj_kernel<<<gOut, 256, 0, stream>>>(ao, Wo, bo, out);
    } else {
        // fallback: use d_out as attention-output scratch, project into qws,
        // then copy back (qws is dead after attention).
        float* ao = out;
        attn_kernel<<<gAttn, 256, 0, stream>>>(qws, kws, vws, ao);
        out_proj_kernel<<<gOut, 256, 0, stream>>>(ao, Wo, bo, qws);
        hipMemcpyAsync(out, qws, per * sizeof(float), hipMemcpyDeviceToDevice,
                       stream);
    }
}

// Round 4
// 665.005 us; speedup vs baseline: 2.6705x; 2.6705x over previous
//
#include <hip/hip_runtime.h>

#define DIMD 512
#define NSEQ 4096
#define BATCH 2
#define NHEADS 8
#define DKH 64
#define LP 72   // LDS pitch (halfwords) for 64-wide tiles: 144B rows -> bank spread

typedef _Float16 h4 __attribute__((ext_vector_type(4)));
typedef _Float16 h8 __attribute__((ext_vector_type(8)));
typedef float f4 __attribute__((ext_vector_type(4)));

struct hl { _Float16 hi, lo; };
__device__ __forceinline__ hl f2hl(float x) {
    hl r;
    r.hi = (_Float16)x;
    r.lo = (_Float16)(x - (float)r.hi);
    return r;
}

// ---------------- fp32 tiled GEMM body (projections) -----------------------------
__device__ __forceinline__ void gemm_body(const float* __restrict__ X,
                                          const float* __restrict__ W,
                                          int m0, int n0, int t,
                                          float (*As)[68], float (*Bs)[64],
                                          float acc[4][4])
{
    const int tx = t & 15, ty = t >> 4;
    for (int k0 = 0; k0 < DIMD; k0 += 16) {
        {
            const int row = t >> 2;
            const int kc = (t & 3) << 2;
            const float4 a = *reinterpret_cast<const float4*>(
                X + (size_t)(m0 + row) * DIMD + k0 + kc);
            As[kc + 0][row] = a.x;
            As[kc + 1][row] = a.y;
            As[kc + 2][row] = a.z;
            As[kc + 3][row] = a.w;
        }
        {
            const float4 b = *reinterpret_cast<const float4*>(
                W + (size_t)(k0 + ty) * DIMD + n0 + (tx << 2));
            *reinterpret_cast<float4*>(&Bs[ty][tx << 2]) = b;
        }
        __syncthreads();
#pragma unroll
        for (int kk = 0; kk < 16; ++kk) {
            const float4 a4 = *reinterpret_cast<const float4*>(&As[kk][ty << 2]);
            const float4 b4 = *reinterpret_cast<const float4*>(&Bs[kk][tx << 2]);
            const float av[4] = {a4.x, a4.y, a4.z, a4.w};
            const float bv[4] = {b4.x, b4.y, b4.z, b4.w};
#pragma unroll
            for (int i = 0; i < 4; ++i)
#pragma unroll
                for (int j = 0; j < 4; ++j)
                    acc[i][j] = fmaf(av[i], bv[j], acc[i][j]);
        }
        __syncthreads();
    }
}

// QKV projection. q,k written head-major [b*H+h][n][dk]; v written TRANSPOSED
// [b*H+h][dk][n] so attention can stage V key-minor with plain vector ops.
__global__ __launch_bounds__(256)
void qkv_proj_kernel(const float* __restrict__ Q, const float* __restrict__ K,
                     const float* __restrict__ V,
                     const float* __restrict__ Wq, const float* __restrict__ bq,
                     const float* __restrict__ Wk, const float* __restrict__ bk,
                     const float* __restrict__ Wv, const float* __restrict__ bv,
                     float* __restrict__ qws, float* __restrict__ kws,
                     float* __restrict__ vws)
{
    __shared__ float As[16][68];
    __shared__ float Bs[16][64];
    const int z = blockIdx.z;
    const float* X    = (z == 0) ? Q  : (z == 1) ? K  : V;
    const float* W    = (z == 0) ? Wq : (z == 1) ? Wk : Wv;
    const float* bias = (z == 0) ? bq : (z == 1) ? bk : bv;

    const int t = threadIdx.x;
    const int tx = t & 15, ty = t >> 4;
    const int m0 = blockIdx.x * 64;
    const int n0 = blockIdx.y * 64;

    float acc[4][4] = {};
    gemm_body(X, W, m0, n0, t, As, Bs, acc);

    const int bb = m0 >> 12;
    const int h  = blockIdx.y;    // 64-wide n-tile == one head
    const size_t hoff = (size_t)(bb * NHEADS + h) * NSEQ * DKH;

    if (z == 2) {
        // transposed store: vt[d_local][key]
        float* op = vws + hoff;
#pragma unroll
        for (int i = 0; i < 4; ++i) {
            const int nrow = (m0 + (ty << 2) + i) & (NSEQ - 1);
#pragma unroll
            for (int c = 0; c < 4; ++c) {
                const int dl = (tx << 2) + c;
                op[(size_t)dl * NSEQ + nrow] = acc[i][c] + bias[n0 + dl];
            }
        }
    } else {
        float* op = ((z == 0) ? qws : kws) + hoff;
#pragma unroll
        for (int i = 0; i < 4; ++i) {
            const int nrow = (m0 + (ty << 2) + i) & (NSEQ - 1);
            float4 o;
            o.x = acc[i][0] + bias[n0 + (tx << 2) + 0];
            o.y = acc[i][1] + bias[n0 + (tx << 2) + 1];
            o.z = acc[i][2] + bias[n0 + (tx << 2) + 2];
            o.w = acc[i][3] + bias[n0 + (tx << 2) + 3];
            *reinterpret_cast<float4*>(op + (size_t)nrow * DKH + (tx << 2)) = o;
        }
    }
}

__global__ __launch_bounds__(256)
void out_proj_kernel(const float* __restrict__ AO, const float* __restrict__ Wo,
                     const float* __restrict__ bo, float* __restrict__ Y)
{
    __shared__ float As[16][68];
    __shared__ float Bs[16][64];
    const int t = threadIdx.x;
    const int tx = t & 15, ty = t >> 4;
    const int m0 = blockIdx.x * 64;
    const int n0 = blockIdx.y * 64;

    float acc[4][4] = {};
    gemm_body(AO, Wo, m0, n0, t, As, Bs, acc);

#pragma unroll
    for (int i = 0; i < 4; ++i) {
        const int m = m0 + (ty << 2) + i;
        float4 o;
        o.x = acc[i][0] + bo[n0 + (tx << 2) + 0];
        o.y = acc[i][1] + bo[n0 + (tx << 2) + 1];
        o.z = acc[i][2] + bo[n0 + (tx << 2) + 2];
        o.w = acc[i][3] + bo[n0 + (tx << 2) + 3];
        *reinterpret_cast<float4*>(Y + (size_t)m * DIMD + n0 + (tx << 2)) = o;
    }
}

// ---------------- MFMA flash attention, fp16 split precision ---------------------
// Block = (b, h, 64 q-rows), 4 waves x 16 q-rows; K-tiles of 64.
// QK^T: 3-pass hi/lo split (exact to ~2^-22). PV: P hi/lo, V single fp16.
// All LDS tiles plain row-major with pitch LP=72 (no swizzle needed).
__global__ __launch_bounds__(256, 3)
void attn_mfma_kernel(const float* __restrict__ qws, const float* __restrict__ kws,
                      const float* __restrict__ vtws, float* __restrict__ ao)
{
    __shared__ __align__(16) _Float16 Ks0[64 * LP];
    __shared__ __align__(16) _Float16 Ks1[64 * LP];
    __shared__ __align__(16) _Float16 Vt [64 * LP];   // [d][key]
    __shared__ __align__(16) _Float16 Ps0[64 * LP];   // Q scratch / per-wave P hi
    __shared__ __align__(16) _Float16 Ps1[64 * LP];   // Q scratch / per-wave P lo

    const int t    = threadIdx.x;
    const int lane = t & 63;
    const int w    = t >> 6;
    const int li   = lane & 15;
    const int lb   = lane >> 4;

    const int id = blockIdx.x;           // 1D grid: h fastest -> XCD/L2 locality
    const int h  = id & 7;
    const int bb = (id >> 3) & 1;
    const int n0 = (id >> 4) << 6;

    const size_t hoff = (size_t)(bb * NHEADS + h) * NSEQ * DKH;
    const float* qh = qws + hoff;
    const float* kh = kws + hoff;
    const float* vh = vtws + hoff;       // [d][key]

    const int srow = t >> 4;             // 0..15
    const int scol = (t & 15) << 2;      // 0..60
    const int dv   = t >> 2;             // 0..63  (V staging: one d row)
    const int kg   = (t & 3) << 4;       // 0,16,32,48

    // ---- stage Q (x 1/8) hi/lo into Ps scratch ----
#pragma unroll
    for (int i = 0; i < 4; ++i) {
        const int row = srow + (i << 4);
        const float4 q = *reinterpret_cast<const float4*>(
            qh + (size_t)(n0 + row) * DKH + scol);
        h4 hi, lo;
        hl t0 = f2hl(q.x * 0.125f); hi[0] = t0.hi; lo[0] = t0.lo;
        hl t1 = f2hl(q.y * 0.125f); hi[1] = t1.hi; lo[1] = t1.lo;
        hl t2 = f2hl(q.z * 0.125f); hi[2] = t2.hi; lo[2] = t2.lo;
        hl t3 = f2hl(q.w * 0.125f); hi[3] = t3.hi; lo[3] = t3.lo;
        *reinterpret_cast<h4*>(&Ps0[row * LP + scol]) = hi;
        *reinterpret_cast<h4*>(&Ps1[row * LP + scol]) = lo;
    }
    __syncthreads();

    // ---- hoist Q fragments: qf[hi/lo][kc], feats kc*32 + lb*8 + j ----
    h8 qf[2][2];
    {
        const int row = w * 16 + li;
#pragma unroll
        for (int kc = 0; kc < 2; ++kc) {
            qf[0][kc] = *reinterpret_cast<const h8*>(&Ps0[row * LP + kc * 32 + lb * 8]);
            qf[1][kc] = *reinterpret_cast<const h8*>(&Ps1[row * LP + kc * 32 + lb * 8]);
        }
    }
    __syncthreads();

    // ---- global prefetch registers ----
    float4 kreg[4], vreg[4];
#define LOAD_TILE(kt)                                                          \
    {                                                                          \
        _Pragma("unroll")                                                      \
        for (int i = 0; i < 4; ++i)                                            \
            kreg[i] = *reinterpret_cast<const float4*>(                        \
                kh + (size_t)((kt) * 64 + srow + (i << 4)) * DKH + scol);      \
        _Pragma("unroll")                                                      \
        for (int u = 0; u < 4; ++u)                                            \
            vreg[u] = *reinterpret_cast<const float4*>(                        \
                vh + (size_t)dv * NSEQ + (kt) * 64 + kg + (u << 2));           \
    }
    LOAD_TILE(0)

    f4 O[4] = {};                        // O[nt][r] = O[q=lb*4+r][d=nt*16+li]
    float mrun[4], lrun[4];
#pragma unroll
    for (int r = 0; r < 4; ++r) { mrun[r] = -3.0e38f; lrun[r] = 0.0f; }

    _Float16* Pw0 = &Ps0[w * 16 * LP];
    _Float16* Pw1 = &Ps1[w * 16 * LP];

    for (int kt = 0; kt < NSEQ / 64; ++kt) {
        // ---- write staged K hi/lo and V^T to LDS ----
#pragma unroll
        for (int i = 0; i < 4; ++i) {
            const int row = srow + (i << 4);
            const float4 k = kreg[i];
            h4 hi, lo;
            hl t0 = f2hl(k.x); hi[0] = t0.hi; lo[0] = t0.lo;
            hl t1 = f2hl(k.y); hi[1] = t1.hi; lo[1] = t1.lo;
            hl t2 = f2hl(k.z); hi[2] = t2.hi; lo[2] = t2.lo;
            hl t3 = f2hl(k.w); hi[3] = t3.hi; lo[3] = t3.lo;
            *reinterpret_cast<h4*>(&Ks0[row * LP + scol]) = hi;
            *reinterpret_cast<h4*>(&Ks1[row * LP + scol]) = lo;
        }
#pragma unroll
        for (int u = 0; u < 4; ++u) {
            const float4 v = vreg[u];
            h4 vv;
            vv[0] = (_Float16)v.x; vv[1] = (_Float16)v.y;
            vv[2] = (_Float16)v.z; vv[3] = (_Float16)v.w;
            *reinterpret_cast<h4*>(&Vt[dv * LP + kg + (u << 2)]) = vv;
        }
        __syncthreads();
        if (kt + 1 < NSEQ / 64) LOAD_TILE(kt + 1)

        // ---- QK^T, 3-pass split ----
        f4 s[4] = {};
#pragma unroll
        for (int kc = 0; kc < 2; ++kc) {
#pragma unroll
            for (int nt = 0; nt < 4; ++nt) {
                const int key = nt * 16 + li;
                const h8 bh = *reinterpret_cast<const h8*>(&Ks0[key * LP + kc * 32 + lb * 8]);
                const h8 bl = *reinterpret_cast<const h8*>(&Ks1[key * LP + kc * 32 + lb * 8]);
                s[nt] = __builtin_amdgcn_mfma_f32_16x16x32_f16(qf[0][kc], bh, s[nt], 0, 0, 0);
                s[nt] = __builtin_amdgcn_mfma_f32_16x16x32_f16(qf[1][kc], bh, s[nt], 0, 0, 0);
                s[nt] = __builtin_amdgcn_mfma_f32_16x16x32_f16(qf[0][kc], bl, s[nt], 0, 0, 0);
            }
        }

        // ---- online softmax; q-row = lb*4+r; keys spread over li x nt ----
        float alpha[4];
#pragma unroll
        for (int r = 0; r < 4; ++r) {
            float mloc = fmaxf(fmaxf(s[0][r], s[1][r]), fmaxf(s[2][r], s[3][r]));
#pragma unroll
            for (int mk = 1; mk < 16; mk <<= 1)
                mloc = fmaxf(mloc, __shfl_xor(mloc, mk));
            const float mnew = fmaxf(mrun[r], mloc);
            alpha[r] = __expf(mrun[r] - mnew);
            mrun[r] = mnew;
            float p0 = __expf(s[0][r] - mnew);
            float p1 = __expf(s[1][r] - mnew);
            float p2 = __expf(s[2][r] - mnew);
            float p3 = __expf(s[3][r] - mnew);
            s[0][r] = p0; s[1][r] = p1; s[2][r] = p2; s[3][r] = p3;
            float ps = p0 + p1 + p2 + p3;
#pragma unroll
            for (int mk = 1; mk < 16; mk <<= 1)
                ps += __shfl_xor(ps, mk);
            lrun[r] = lrun[r] * alpha[r] + ps;
        }
#pragma unroll
        for (int nt = 0; nt < 4; ++nt) {
            O[nt][0] *= alpha[0]; O[nt][1] *= alpha[1];
            O[nt][2] *= alpha[2]; O[nt][3] *= alpha[3];
        }

        // ---- write P hi/lo to this wave's region (rows = q 0..15, key-minor) ----
#pragma unroll
        for (int nt = 0; nt < 4; ++nt) {
#pragma unroll
            for (int r = 0; r < 4; ++r) {
                const float p = s[nt][r];
                const _Float16 ph = (_Float16)p;
                const _Float16 pl = (_Float16)(p - (float)ph);
                const int a = (lb * 4 + r) * LP + nt * 16 + li;
                Pw0[a] = ph;
                Pw1[a] = pl;
            }
        }

        // ---- PV: O += (P_hi + P_lo) * V ----
#pragma unroll
        for (int kc = 0; kc < 2; ++kc) {
            const h8 pA = *reinterpret_cast<const h8*>(&Pw0[li * LP + kc * 32 + lb * 8]);
            const h8 pL = *reinterpret_cast<const h8*>(&Pw1[li * LP + kc * 32 + lb * 8]);
#pragma unroll
            for (int nt = 0; nt < 4; ++nt) {
                const int d = nt * 16 + li;
                const h8 vB = *reinterpret_cast<const h8*>(&Vt[d * LP + kc * 32 + lb * 8]);
                O[nt] = __builtin_amdgcn_mfma_f32_16x16x32_f16(pA, vB, O[nt], 0, 0, 0);
                O[nt] = __builtin_amdgcn_mfma_f32_16x16x32_f16(pL, vB, O[nt], 0, 0, 0);
            }
        }
        __syncthreads();
    }

    // ---- epilogue: normalize, write [B][N][D] ----
#pragma unroll
    for (int r = 0; r < 4; ++r) {
        const float inv = 1.0f / lrun[r];
        const int orow = n0 + w * 16 + lb * 4 + r;
        float* op = ao + ((size_t)bb * NSEQ + orow) * DIMD + h * DKH;
        op[0 * 16 + li] = O[0][r] * inv;
        op[1 * 16 + li] = O[1][r] * inv;
        op[2 * 16 + li] = O[2][r] * inv;
        op[3 * 16 + li] = O[3][r] * inv;
    }
}

extern "C" void kernel_launch(void* const* d_in, const int* in_sizes, int n_in,
                              void* d_out, int out_size, void* d_ws, size_t ws_size,
                              hipStream_t stream) {
    const float* Q  = (const float*)d_in[0];
    const float* K  = (const float*)d_in[1];
    const float* V  = (const float*)d_in[2];
    const float* Wq = (const float*)d_in[3];
    const float* bq = (const float*)d_in[4];
    const float* Wk = (const float*)d_in[5];
    const float* bk = (const float*)d_in[6];
    const float* Wv = (const float*)d_in[7];
    const float* bv = (const float*)d_in[8];
    const float* Wo = (const float*)d_in[9];
    const float* bo = (const float*)d_in[10];
    float* out = (float*)d_out;
    float* ws  = (float*)d_ws;

    const size_t per = (size_t)BATCH * NSEQ * DIMD;   // 4,194,304 floats
    float* qws = ws;
    float* kws = ws + per;
    float* vws = ws + 2 * per;   // holds V^T per head

    const dim3 gProj(BATCH * NSEQ / 64, DIMD / 64, 3);
    const dim3 gAttn(BATCH * NSEQ / 64 * NHEADS, 1, 1);   // 1024, h in low bits
    const dim3 gOut(BATCH * NSEQ / 64, DIMD / 64, 1);

    qkv_proj_kernel<<<gProj, 256, 0, stream>>>(Q, K, V, Wq, bq, Wk, bk, Wv, bv,
                                               qws, kws, vws);

    if (ws_size >= 4 * per * sizeof(float)) {
        float* ao = ws + 3 * per;
        attn_mfma_kernel<<<gAttn, 256, 0, stream>>>(qws, kws, vws, ao);
        out_proj_kernel<<<gOut, 256, 0, stream>>>(ao, Wo, bo, out);
    } else {
        float* ao = out;
        attn_mfma_kernel<<<gAttn, 256, 0, stream>>>(qws, kws, vws, ao);
        out_proj_kernel<<<gOut, 256, 0, stream>>>(ao, Wo, bo, qws);
        (void)hipMemcpyAsync(out, qws, per * sizeof(float),
                             hipMemcpyDeviceToDevice, stream);
    }
}

// Round 7
// 582.085 us; speedup vs baseline: 3.0509x; 1.1425x over previous
//
#include <hip/hip_runtime.h>

#define DIMD 512
#define NSEQ 4096
#define BATCH 2
#define NHEADS 8
#define DKH 64
#define NT (NSEQ / 64)          // 64 key tiles
// kimg: per bh: 64 tiles x 8192 halfwords (Khi 4096 | Klo 4096), swizzled rows
// vimg: per bh: 64 tiles x 4096 halfwords (V^T [d][key]), swizzled rows
#define KIMG_BH 524288
#define VIMG_BH 262144

typedef _Float16 h4 __attribute__((ext_vector_type(4)));
typedef _Float16 h8 __attribute__((ext_vector_type(8)));
typedef float f4 __attribute__((ext_vector_type(4)));

struct hl { _Float16 hi, lo; };
__device__ __forceinline__ hl f2hl(float x) {
    hl r;
    r.hi = (_Float16)x;
    r.lo = (_Float16)(x - (float)r.hi);
    return r;
}

__device__ __forceinline__ void gld16(const void* g, void* l) {
    __builtin_amdgcn_global_load_lds(
        (const __attribute__((address_space(1))) void*)g,
        (__attribute__((address_space(3))) void*)l, 16, 0, 0);
}

// ---------------- fp32 tiled GEMM body (projections) -----------------------------
__device__ __forceinline__ void gemm_body(const float* __restrict__ X,
                                          const float* __restrict__ W,
                                          int m0, int n0, int t,
                                          float (*As)[68], float (*Bs)[64],
                                          float acc[4][4])
{
    const int tx = t & 15, ty = t >> 4;
    for (int k0 = 0; k0 < DIMD; k0 += 16) {
        {
            const int row = t >> 2;
            const int kc = (t & 3) << 2;
            const float4 a = *reinterpret_cast<const float4*>(
                X + (size_t)(m0 + row) * DIMD + k0 + kc);
            As[kc + 0][row] = a.x;
            As[kc + 1][row] = a.y;
            As[kc + 2][row] = a.z;
            As[kc + 3][row] = a.w;
        }
        {
            const float4 b = *reinterpret_cast<const float4*>(
                W + (size_t)(k0 + ty) * DIMD + n0 + (tx << 2));
            *reinterpret_cast<float4*>(&Bs[ty][tx << 2]) = b;
        }
        __syncthreads();
#pragma unroll
        for (int kk = 0; kk < 16; ++kk) {
            const float4 a4 = *reinterpret_cast<const float4*>(&As[kk][ty << 2]);
            const float4 b4 = *reinterpret_cast<const float4*>(&Bs[kk][tx << 2]);
            const float av[4] = {a4.x, a4.y, a4.z, a4.w};
            const float bv[4] = {b4.x, b4.y, b4.z, b4.w};
#pragma unroll
            for (int i = 0; i < 4; ++i)
#pragma unroll
                for (int j = 0; j < 4; ++j)
                    acc[i][j] = fmaf(av[i], bv[j], acc[i][j]);
        }
        __syncthreads();
    }
}

// QKV projection. Q -> fp32 head-major [bh][n][64].
// K -> packed fp16 hi/lo tile images, XOR-swizzled chunks (attn LDS layout).
// V -> packed fp16 V^T tile images, XOR-swizzled.
__global__ __launch_bounds__(256)
void qkv_proj_kernel(const float* __restrict__ Q, const float* __restrict__ K,
                     const float* __restrict__ V,
                     const float* __restrict__ Wq, const float* __restrict__ bq,
                     const float* __restrict__ Wk, const float* __restrict__ bk,
                     const float* __restrict__ Wv, const float* __restrict__ bv,
                     float* __restrict__ qws, _Float16* __restrict__ kimg,
                     _Float16* __restrict__ vimg)
{
    __shared__ float As[16][68];
    __shared__ float Bs[16][64];
    const int z = blockIdx.z;
    const float* X    = (z == 0) ? Q  : (z == 1) ? K  : V;
    const float* W    = (z == 0) ? Wq : (z == 1) ? Wk : Wv;
    const float* bias = (z == 0) ? bq : (z == 1) ? bk : bv;

    const int t = threadIdx.x;
    const int tx = t & 15, ty = t >> 4;
    const int m0 = blockIdx.x * 64;
    const int n0 = blockIdx.y * 64;

    float acc[4][4] = {};
    gemm_body(X, W, m0, n0, t, As, Bs, acc);

    const int bb = m0 >> 12;
    const int h  = blockIdx.y;
    const int bh = bb * NHEADS + h;
    const int kt = (m0 & (NSEQ - 1)) >> 6;

    if (z == 0) {
        float* op = qws + (size_t)bh * NSEQ * DKH;
#pragma unroll
        for (int i = 0; i < 4; ++i) {
            const int nrow = (m0 + (ty << 2) + i) & (NSEQ - 1);
            float4 o;
            o.x = acc[i][0] + bias[n0 + (tx << 2) + 0];
            o.y = acc[i][1] + bias[n0 + (tx << 2) + 1];
            o.z = acc[i][2] + bias[n0 + (tx << 2) + 2];
            o.w = acc[i][3] + bias[n0 + (tx << 2) + 3];
            *reinterpret_cast<float4*>(op + (size_t)nrow * DKH + (tx << 2)) = o;
        }
    } else if (z == 1) {
        _Float16* kb = kimg + (size_t)bh * KIMG_BH + (size_t)kt * 8192;
#pragma unroll
        for (int i = 0; i < 4; ++i) {
            const int key = (ty << 2) + i;              // key within tile
            h4 hi, lo;
#pragma unroll
            for (int j = 0; j < 4; ++j) {
                hl s = f2hl(acc[i][j] + bias[n0 + (tx << 2) + j]);
                hi[j] = s.hi; lo[j] = s.lo;
            }
            const int a = (key << 6) + (((tx >> 1) ^ (key & 7)) << 3) + ((tx & 1) << 2);
            *reinterpret_cast<h4*>(&kb[a])        = hi;
            *reinterpret_cast<h4*>(&kb[4096 + a]) = lo;
        }
    } else {
        _Float16* vb = vimg + (size_t)bh * VIMG_BH + (size_t)kt * 4096;
#pragma unroll
        for (int c = 0; c < 4; ++c) {
            const int d = (tx << 2) + c;
            const float bd = bias[n0 + d];
            h4 vv;
#pragma unroll
            for (int i = 0; i < 4; ++i)
                vv[i] = (_Float16)(acc[i][c] + bd);     // keys ty*4+i
            const int a = (d << 6) + (((ty >> 1) ^ (d & 7)) << 3) + ((ty & 1) << 2);
            *reinterpret_cast<h4*>(&vb[a]) = vv;
        }
    }
}

__global__ __launch_bounds__(256)
void out_proj_kernel(const float* __restrict__ AO, const float* __restrict__ Wo,
                     const float* __restrict__ bo, float* __restrict__ Y)
{
    __shared__ float As[16][68];
    __shared__ float Bs[16][64];
    const int t = threadIdx.x;
    const int tx = t & 15, ty = t >> 4;
    const int m0 = blockIdx.x * 64;
    const int n0 = blockIdx.y * 64;

    float acc[4][4] = {};
    gemm_body(AO, Wo, m0, n0, t, As, Bs, acc);

#pragma unroll
    for (int i = 0; i < 4; ++i) {
        const int m = m0 + (ty << 2) + i;
        float4 o;
        o.x = acc[i][0] + bo[n0 + (tx << 2) + 0];
        o.y = acc[i][1] + bo[n0 + (tx << 2) + 1];
        o.z = acc[i][2] + bo[n0 + (tx << 2) + 2];
        o.w = acc[i][3] + bo[n0 + (tx << 2) + 3];
        *reinterpret_cast<float4*>(Y + (size_t)m * DIMD + n0 + (tx << 2)) = o;
    }
}

// ---------------- MFMA flash attention -------------------------------------------
// Block = 128 q-rows of one (b,h); 4 waves x 32 q (2 frags of 16). K-tiles of 64.
// K/V staged by async global_load_lds from pre-converted, pre-swizzled fp16 images
// (double-buffered, stage-after-barrier: 1 barrier per tile, loads in flight
// across the whole compute phase). QK^T 3-pass fp16 split; PV P-hi/lo, V fp16.
__global__ __launch_bounds__(256, 2)
void attn_mfma_kernel(const float* __restrict__ qws,
                      const _Float16* __restrict__ kimg,
                      const _Float16* __restrict__ vimg,
                      float* __restrict__ ao)
{
    // KV[buf]: bytes [0,16384) = Khi|Klo, [16384,24576) = V^T    48 KB total
    __shared__ __align__(16) _Float16 KV[2][12288];
    __shared__ __align__(16) _Float16 P0[128 * 64];   // Q-hi scratch / P-hi 16 KB
    __shared__ __align__(16) _Float16 P1[128 * 64];   // Q-lo scratch / P-lo 16 KB

    const int t    = threadIdx.x;
    const int lane = t & 63;
    const int w    = t >> 6;
    const int li   = lane & 15;
    const int lb   = lane >> 4;

    const int id = blockIdx.x;            // h in low 3 bits -> XCD L2 locality
    const int h  = id & 7;
    const int bb = (id >> 3) & 1;
    const int q0 = (id >> 4) << 7;
    const int bh = bb * NHEADS + h;

    const float*    qh  = qws + (size_t)bh * NSEQ * DKH;
    const _Float16* kin = kimg + (size_t)bh * KIMG_BH;
    const _Float16* vin = vimg + (size_t)bh * VIMG_BH;

    const int tx = t & 15;
    const int scol = tx << 2;

    // ---- stage Q (x 1/8) hi/lo into P0/P1 (swizzled, pitch 64) ----
#pragma unroll
    for (int ps = 0; ps < 8; ++ps) {
        const int row = (t >> 4) + (ps << 4);
        const float4 q = *reinterpret_cast<const float4*>(
            qh + (size_t)(q0 + row) * DKH + scol);
        h4 hi, lo;
        hl s0 = f2hl(q.x * 0.125f); hi[0] = s0.hi; lo[0] = s0.lo;
        hl s1 = f2hl(q.y * 0.125f); hi[1] = s1.hi; lo[1] = s1.lo;
        hl s2 = f2hl(q.z * 0.125f); hi[2] = s2.hi; lo[2] = s2.lo;
        hl s3 = f2hl(q.w * 0.125f); hi[3] = s3.hi; lo[3] = s3.lo;
        const int a = (row << 6) + (((tx >> 1) ^ (row & 7)) << 3) + ((tx & 1) << 2);
        *reinterpret_cast<h4*>(&P0[a]) = hi;
        *reinterpret_cast<h4*>(&P1[a]) = lo;
    }
    __syncthreads();

#define STAGE(kt, buf)                                                          \
    {                                                                           \
        const char* kg = (const char*)kin + (size_t)(kt) * 16384 + (w << 12);   \
        const char* vg = (const char*)vin + (size_t)(kt) * 8192 + (w << 11);    \
        char* lk = (char*)&KV[buf][0] + (w << 12);                              \
        char* lv = (char*)&KV[buf][0] + 16384 + (w << 11);                      \
        const int l16 = lane << 4;                                              \
        gld16(kg + l16,        lk);                                             \
        gld16(kg + 1024 + l16, lk + 1024);                                      \
        gld16(kg + 2048 + l16, lk + 2048);                                      \
        gld16(kg + 3072 + l16, lk + 3072);                                      \
        gld16(vg + l16,        lv);                                             \
        gld16(vg + 1024 + l16, lv + 1024);                                      \
    }

    STAGE(0, 0)

    // ---- hoist Q fragments ----
    h8 qrh[2][2], qrl[2][2];
#pragma unroll
    for (int qf = 0; qf < 2; ++qf) {
        const int row = (w << 5) + (qf << 4) + li;
#pragma unroll
        for (int kc = 0; kc < 2; ++kc) {
            const int a = (row << 6) + ((((kc << 2) + lb) ^ (row & 7)) << 3);
            qrh[qf][kc] = *reinterpret_cast<const h8*>(&P0[a]);
            qrl[qf][kc] = *reinterpret_cast<const h8*>(&P1[a]);
        }
    }

    f4 O[2][4] = {};
    float mrun[2][4], lpart[2][4];
#pragma unroll
    for (int qf = 0; qf < 2; ++qf)
#pragma unroll
        for (int r = 0; r < 4; ++r) { mrun[qf][r] = -3.0e38f; lpart[qf][r] = 0.0f; }

    for (int kt = 0; kt < NT; ++kt) {
        const int p = kt & 1;
        __syncthreads();                  // drains prev stage loads (vmcnt 0)
        if (kt + 1 < NT) STAGE(kt + 1, p ^ 1)

        const _Float16* Kp = &KV[p][0];
        const _Float16* Vp = &KV[p][8192];

        // ---- QK^T, 3-pass split; K frags reused across 2 q-frags ----
        f4 s[2][4] = {};
#pragma unroll
        for (int kc = 0; kc < 2; ++kc) {
#pragma unroll
            for (int nt = 0; nt < 4; ++nt) {
                const int key = (nt << 4) + li;
                const int a = (key << 6) + ((((kc << 2) + lb) ^ (key & 7)) << 3);
                const h8 bh8 = *reinterpret_cast<const h8*>(&Kp[a]);
                const h8 bl8 = *reinterpret_cast<const h8*>(&Kp[4096 + a]);
#pragma unroll
                for (int qf = 0; qf < 2; ++qf) {
                    s[qf][nt] = __builtin_amdgcn_mfma_f32_16x16x32_f16(qrh[qf][kc], bh8, s[qf][nt], 0, 0, 0);
                    s[qf][nt] = __builtin_amdgcn_mfma_f32_16x16x32_f16(qrl[qf][kc], bh8, s[qf][nt], 0, 0, 0);
                    s[qf][nt] = __builtin_amdgcn_mfma_f32_16x16x32_f16(qrh[qf][kc], bl8, s[qf][nt], 0, 0, 0);
                }
            }
        }

        // ---- online softmax (defer-max exact skip; lane-local l partials) ----
#pragma unroll
        for (int qf = 0; qf < 2; ++qf) {
            float ml[4];
#pragma unroll
            for (int r = 0; r < 4; ++r) {
                float m_ = fmaxf(fmaxf(s[qf][0][r], s[qf][1][r]),
                                 fmaxf(s[qf][2][r], s[qf][3][r]));
#pragma unroll
                for (int mk = 1; mk < 16; mk <<= 1)
                    m_ = fmaxf(m_, __shfl_xor(m_, mk));
                ml[r] = m_;
            }
            const int grow = (ml[0] > mrun[qf][0]) | (ml[1] > mrun[qf][1]) |
                             (ml[2] > mrun[qf][2]) | (ml[3] > mrun[qf][3]);
            if (__any(grow)) {
#pragma unroll
                for (int r = 0; r < 4; ++r) {
                    const float mnew  = fmaxf(mrun[qf][r], ml[r]);
                    const float alpha = __expf(mrun[qf][r] - mnew);
                    mrun[qf][r] = mnew;
                    lpart[qf][r] *= alpha;
#pragma unroll
                    for (int nt = 0; nt < 4; ++nt) O[qf][nt][r] *= alpha;
                }
            }
#pragma unroll
            for (int nt = 0; nt < 4; ++nt)
#pragma unroll
                for (int r = 0; r < 4; ++r) {
                    const float pv = __expf(s[qf][nt][r] - mrun[qf][r]);
                    s[qf][nt][r] = pv;
                    lpart[qf][r] += pv;
                }
            // P write (hi/lo, swizzled pitch-64)
#pragma unroll
            for (int nt = 0; nt < 4; ++nt) {
                const int key = (nt << 4) + li;
                const int cc = key >> 3, oo = key & 7;
#pragma unroll
                for (int r = 0; r < 4; ++r) {
                    const int row = (w << 5) + (qf << 4) + (lb << 2) + r;
                    const int a = (row << 6) + ((cc ^ (row & 7)) << 3) + oo;
                    const float pv = s[qf][nt][r];
                    const _Float16 ph = (_Float16)pv;
                    P0[a] = ph;
                    P1[a] = (_Float16)(pv - (float)ph);
                }
            }
        }

        // ---- PV: O += (P_hi + P_lo) * V; V frags reused across q-frags ----
#pragma unroll
        for (int kc = 0; kc < 2; ++kc) {
            h8 vB[4];
#pragma unroll
            for (int nt = 0; nt < 4; ++nt) {
                const int d = (nt << 4) + li;
                vB[nt] = *reinterpret_cast<const h8*>(
                    &Vp[(d << 6) + ((((kc << 2) + lb) ^ (d & 7)) << 3)]);
            }
#pragma unroll
            for (int qf = 0; qf < 2; ++qf) {
                const int row = (w << 5) + (qf << 4) + li;
                const int a = (row << 6) + ((((kc << 2) + lb) ^ (row & 7)) << 3);
                const h8 pA = *reinterpret_cast<const h8*>(&P0[a]);
                const h8 pL = *reinterpret_cast<const h8*>(&P1[a]);
#pragma unroll
                for (int nt = 0; nt < 4; ++nt) {
                    O[qf][nt] = __builtin_amdgcn_mfma_f32_16x16x32_f16(pA, vB[nt], O[qf][nt], 0, 0, 0);
                    O[qf][nt] = __builtin_amdgcn_mfma_f32_16x16x32_f16(pL, vB[nt], O[qf][nt], 0, 0, 0);
                }
            }
        }
    }

    // ---- epilogue: reduce l, normalize, write [B][N][D] ----
#pragma unroll
    for (int qf = 0; qf < 2; ++qf)
#pragma unroll
        for (int r = 0; r < 4; ++r) {
            float l = lpart[qf][r];
#pragma unroll
            for (int mk = 1; mk < 16; mk <<= 1) l += __shfl_xor(l, mk);
            const float inv = 1.0f / l;
            const int orow = q0 + (w << 5) + (qf << 4) + (lb << 2) + r;
            float* op = ao + ((size_t)bb * NSEQ + orow) * DIMD + (h << 6);
            op[0 * 16 + li] = O[qf][0][r] * inv;
            op[1 * 16 + li] = O[qf][1][r] * inv;
            op[2 * 16 + li] = O[qf][2][r] * inv;
            op[3 * 16 + li] = O[qf][3][r] * inv;
        }
}

extern "C" void kernel_launch(void* const* d_in, const int* in_sizes, int n_in,
                              void* d_out, int out_size, void* d_ws, size_t ws_size,
                              hipStream_t stream) {
    const float* Q  = (const float*)d_in[0];
    const float* K  = (const float*)d_in[1];
    const float* V  = (const float*)d_in[2];
    const float* Wq = (const float*)d_in[3];
    const float* bq = (const float*)d_in[4];
    const float* Wk = (const float*)d_in[5];
    const float* bk = (const float*)d_in[6];
    const float* Wv = (const float*)d_in[7];
    const float* bv = (const float*)d_in[8];
    const float* Wo = (const float*)d_in[9];
    const float* bo = (const float*)d_in[10];
    float* out = (float*)d_out;
    float* ws  = (float*)d_ws;

    const size_t perQ = (size_t)BATCH * NSEQ * DIMD;          // 4,194,304 floats
    float*     qws  = ws;
    _Float16*  kimg = (_Float16*)(ws + perQ);                 // 8,388,608 halfwords
    _Float16*  vimg = kimg + (size_t)16 * KIMG_BH;            // 4,194,304 halfwords
    float*     aoP  = (float*)(vimg + (size_t)16 * VIMG_BH);  // 4,194,304 floats

    const size_t need = (perQ + perQ + perQ / 2 + perQ) * sizeof(float);

    const dim3 gProj(BATCH * NSEQ / 64, DIMD / 64, 3);
    const dim3 gAttn(BATCH * NSEQ / 128 * NHEADS, 1, 1);      // 512, h in low bits
    const dim3 gOut(BATCH * NSEQ / 64, DIMD / 64, 1);

    qkv_proj_kernel<<<gProj, 256, 0, stream>>>(Q, K, V, Wq, bq, Wk, bk, Wv, bv,
                                               qws, kimg, vimg);

    if (ws_size >= need) {
        attn_mfma_kernel<<<gAttn, 256, 0, stream>>>(qws, kimg, vimg, aoP);
        out_proj_kernel<<<gOut, 256, 0, stream>>>(aoP, Wo, bo, out);
    } else {
        float* aoF = out;   // fallback: use d_out as attention scratch
        attn_mfma_kernel<<<gAttn, 256, 0, stream>>>(qws, kimg, vimg, aoF);
        out_proj_kernel<<<gOut, 256, 0, stream>>>(aoF, Wo, bo, qws);
        (void)hipMemcpyAsync(out, qws, perQ * sizeof(float),
                             hipMemcpyDeviceToDevice, stream);
    }
}

// Round 8
// 364.273 us; speedup vs baseline: 4.8752x; 1.5979x over previous
//
#include <hip/hip_runtime.h>

#define NSEQ 4096
#define BATCH 2
#define NHEADS 8
#define QSCALE 0.18033688f   // log2(e)/8  (folds softmax scale + exp2 domain into Q)

typedef _Float16 h4 __attribute__((ext_vector_type(4)));
typedef _Float16 h8 __attribute__((ext_vector_type(8)));
typedef float f4 __attribute__((ext_vector_type(4)));

// image geometry (halfwords)
#define XIMG_Z   4194304u    // per-z A image: 64 mt x 8 kt x 8192
#define WIMG_W   262144u     // per-weight B image: 8 ntile x 8 kt x 4096
#define HIMG_BH  262144u     // per-bh q/k/v image: 4096 x 64

__device__ __forceinline__ void gld16(const void* g, void* l) {
    __builtin_amdgcn_global_load_lds(
        (const __attribute__((address_space(1))) void*)g,
        (__attribute__((address_space(3))) void*)l, 16, 0, 0);
}

// ---------------- cvt kernels: build pre-swizzled fp16 images --------------------
// A-image tile (128 rows x 64 k): addr = (row<<6) + ((chunk^(row&7))<<3) + off
__global__ __launch_bounds__(256)
void cvt_x_kernel(const float* __restrict__ Q, const float* __restrict__ K,
                  const float* __restrict__ V, _Float16* __restrict__ ximg)
{
    const int z = blockIdx.y;
    const float* X = (z == 0) ? Q : (z == 1) ? K : V;
    const int e = blockIdx.x * 256 + threadIdx.x;      // float4 index, 0..1048575
    const int m  = e >> 7;
    const int k0 = (e & 127) << 2;
    const float4 v = *reinterpret_cast<const float4*>(X + (size_t)m * 512 + k0);
    h4 hv;
    hv[0] = (_Float16)v.x; hv[1] = (_Float16)v.y;
    hv[2] = (_Float16)v.z; hv[3] = (_Float16)v.w;
    const int mt = m >> 7, row = m & 127, kt = k0 >> 6, kk = k0 & 63;
    const int chunk = kk >> 3, half = (kk >> 2) & 1;
    _Float16* dst = ximg + (size_t)z * XIMG_Z + ((size_t)mt * 8 + kt) * 8192;
    dst[(row << 6) + ((chunk ^ (row & 7)) << 3) + (half << 2) + 0] = hv[0];
    // vector write (8B aligned)
    *reinterpret_cast<h4*>(&dst[(row << 6) + ((chunk ^ (row & 7)) << 3) + (half << 2)]) = hv;
}

// B-image: W^T tiles (64 n-rows x 64 k)
__global__ __launch_bounds__(256)
void cvt_w_kernel(const float* __restrict__ Wq, const float* __restrict__ Wk,
                  const float* __restrict__ Wv, const float* __restrict__ Wo,
                  _Float16* __restrict__ wimg)
{
    const int which = blockIdx.y;
    const float* W = (which == 0) ? Wq : (which == 1) ? Wk : (which == 2) ? Wv : Wo;
    const int e = blockIdx.x * 256 + threadIdx.x;      // 0..65535
    const int k  = e >> 7;
    const int n0 = (e & 127) << 2;
    const float4 v = *reinterpret_cast<const float4*>(W + (size_t)k * 512 + n0);
    _Float16* wb = wimg + (size_t)which * WIMG_W;
    const int kt = k >> 6, kk = k & 63, chunk = kk >> 3, oo = kk & 7;
    const float vv[4] = {v.x, v.y, v.z, v.w};
#pragma unroll
    for (int c = 0; c < 4; ++c) {
        const int n = n0 + c, ntile = n >> 6, nr = n & 63;
        wb[((size_t)ntile * 8 + kt) * 4096 +
           (nr << 6) + ((chunk ^ (nr & 7)) << 3) + oo] = (_Float16)vv[c];
    }
}

// ---------------- fp16 MFMA GEMM: C = A·B (B staged as B^T rows) -----------------
// Block: 128 m-rows x 64 n-cols, 4 waves x 32 rows (2 qf), k-loop 8 x 64.
#define GEMM_BODY(At, Bt, acc)                                                   \
    GSTAGE(0, 0)                                                                 \
    for (int kt = 0; kt < 8; ++kt) {                                             \
        const int p = kt & 1;                                                    \
        __syncthreads();                                                         \
        if (kt + 1 < 8) GSTAGE(kt + 1, p ^ 1)                                    \
        _Pragma("unroll")                                                        \
        for (int kc = 0; kc < 2; ++kc) {                                         \
            h8 af[2];                                                            \
            _Pragma("unroll")                                                    \
            for (int qf = 0; qf < 2; ++qf) {                                     \
                const int row = (w << 5) + (qf << 4) + li;                       \
                af[qf] = *reinterpret_cast<const h8*>(                           \
                    &Ab[p][(row << 6) + ((((kc << 2) + lb) ^ (row & 7)) << 3)]); \
            }                                                                    \
            _Pragma("unroll")                                                    \
            for (int nt = 0; nt < 4; ++nt) {                                     \
                const int nr = (nt << 4) + li;                                   \
                const h8 bf = *reinterpret_cast<const h8*>(                      \
                    &Bb[p][(nr << 6) + ((((kc << 2) + lb) ^ (nr & 7)) << 3)]);   \
                _Pragma("unroll")                                                \
                for (int qf = 0; qf < 2; ++qf)                                   \
                    acc[qf][nt] = __builtin_amdgcn_mfma_f32_16x16x32_f16(        \
                        af[qf], bf, acc[qf][nt], 0, 0, 0);                       \
            }                                                                    \
        }                                                                        \
    }

#define GSTAGE(kt, buf)                                                          \
    {                                                                            \
        const char* ag = (const char*)(At + (size_t)(kt) * 8192) + (w << 12);    \
        const char* bg = (const char*)(Bt + (size_t)(kt) * 4096) + (w << 11);    \
        char* la  = (char*)&Ab[buf][0] + (w << 12);                              \
        char* lbp = (char*)&Bb[buf][0] + (w << 11);                              \
        const int l16 = lane << 4;                                               \
        gld16(ag + l16, la);               gld16(ag + 1024 + l16, la + 1024);    \
        gld16(ag + 2048 + l16, la + 2048); gld16(ag + 3072 + l16, la + 3072);    \
        gld16(bg + l16, lbp);              gld16(bg + 1024 + l16, lbp + 1024);   \
    }

// QKV projection GEMM: z=0 -> qimg (scaled fp16), z=1 -> kimg, z=2 -> vimg(V^T)
__global__ __launch_bounds__(256, 3)
void qkv_gemm_kernel(const _Float16* __restrict__ ximg,
                     const _Float16* __restrict__ wimg,
                     const float* __restrict__ bq, const float* __restrict__ bk,
                     const float* __restrict__ bv,
                     _Float16* __restrict__ qimg, _Float16* __restrict__ kimg,
                     _Float16* __restrict__ vimg)
{
    __shared__ __align__(16) _Float16 Ab[2][8192];
    __shared__ __align__(16) _Float16 Bb[2][4096];
    const int t = threadIdx.x, lane = t & 63, w = t >> 6;
    const int li = lane & 15, lb = lane >> 4;
    const int mt = blockIdx.x, nb = blockIdx.y, z = blockIdx.z;

    const _Float16* At = ximg + (size_t)z * XIMG_Z + (size_t)mt * 8 * 8192;
    const _Float16* Bt = wimg + (size_t)z * WIMG_W + (size_t)nb * 8 * 4096;
    const float* bias = (z == 0) ? bq : (z == 1) ? bk : bv;

    f4 acc[2][4] = {};
    GEMM_BODY(At, Bt, acc)

#pragma unroll
    for (int qf = 0; qf < 2; ++qf)
#pragma unroll
        for (int r = 0; r < 4; ++r) {
            const int m  = mt * 128 + (w << 5) + (qf << 4) + (lb << 2) + r;
            const int bh = (m >> 12) * NHEADS + nb;   // nb == head for qkv
            const int sr = m & (NSEQ - 1);
#pragma unroll
            for (int nt = 0; nt < 4; ++nt) {
                const int dl = (nt << 4) + li;         // 0..63 within head
                const float val = acc[qf][nt][r] + bias[nb * 64 + dl];
                if (z == 0) {
                    qimg[(size_t)bh * HIMG_BH + (size_t)sr * 64 + dl] =
                        (_Float16)(val * QSCALE);
                } else if (z == 1) {
                    const int ktile = sr >> 6, key = sr & 63;
                    kimg[(size_t)bh * HIMG_BH + (size_t)ktile * 4096 +
                         (key << 6) + (((dl >> 3) ^ (key & 7)) << 3) + (dl & 7)] =
                        (_Float16)val;
                } else {
                    const int ktile = sr >> 6, key = sr & 63;
                    vimg[(size_t)bh * HIMG_BH + (size_t)ktile * 4096 +
                         (dl << 6) + (((key >> 3) ^ (dl & 7)) << 3) + (key & 7)] =
                        (_Float16)val;
                }
            }
        }
}

// Output projection GEMM: Y = AO@Wo + bo (fp32 out)
__global__ __launch_bounds__(256, 3)
void out_gemm_kernel(const _Float16* __restrict__ aoimg,
                     const _Float16* __restrict__ wimg,
                     const float* __restrict__ bo, float* __restrict__ Y)
{
    __shared__ __align__(16) _Float16 Ab[2][8192];
    __shared__ __align__(16) _Float16 Bb[2][4096];
    const int t = threadIdx.x, lane = t & 63, w = t >> 6;
    const int li = lane & 15, lb = lane >> 4;
    const int mt = blockIdx.x, nb = blockIdx.y;

    const _Float16* At = aoimg + (size_t)mt * 8 * 8192;
    const _Float16* Bt = wimg + (size_t)3 * WIMG_W + (size_t)nb * 8 * 4096;

    f4 acc[2][4] = {};
    GEMM_BODY(At, Bt, acc)

#pragma unroll
    for (int qf = 0; qf < 2; ++qf)
#pragma unroll
        for (int r = 0; r < 4; ++r) {
            const int m = mt * 128 + (w << 5) + (qf << 4) + (lb << 2) + r;
#pragma unroll
            for (int nt = 0; nt < 4; ++nt) {
                const int n = nb * 64 + (nt << 4) + li;
                Y[(size_t)m * 512 + n] = acc[qf][nt][r] + bo[n];
            }
        }
}

// ---------------- MFMA flash attention, pure fp16, exp2 softmax ------------------
__global__ __launch_bounds__(256, 3)
void attn_mfma_kernel(const _Float16* __restrict__ qimg,
                      const _Float16* __restrict__ kimg,
                      const _Float16* __restrict__ vimg,
                      _Float16* __restrict__ aoimg)
{
    __shared__ __align__(16) _Float16 KB[2][4096];
    __shared__ __align__(16) _Float16 VB[2][4096];
    __shared__ __align__(16) _Float16 P0[8192];     // 128 x 64, swizzled

    const int t = threadIdx.x, lane = t & 63, w = t >> 6;
    const int li = lane & 15, lb = lane >> 4;

    const int id = blockIdx.x;            // h in low bits -> XCD L2 locality
    const int h  = id & 7;
    const int bb = (id >> 3) & 1;
    const int q0 = (id >> 4) << 7;
    const int bh = bb * NHEADS + h;

    const _Float16* qh  = qimg + (size_t)bh * HIMG_BH;
    const _Float16* kin = kimg + (size_t)bh * HIMG_BH;
    const _Float16* vin = vimg + (size_t)bh * HIMG_BH;

    // Q fragments straight from global (tiny volume, L2/L3-resident)
    h8 qr[2][2];
#pragma unroll
    for (int qf = 0; qf < 2; ++qf)
#pragma unroll
        for (int kc = 0; kc < 2; ++kc) {
            const int row = q0 + (w << 5) + (qf << 4) + li;
            qr[qf][kc] = *reinterpret_cast<const h8*>(
                qh + (size_t)row * 64 + (kc << 5) + (lb << 3));
        }

#define STAGE(kt, buf)                                                          \
    {                                                                           \
        const char* kg = (const char*)(kin + (size_t)(kt) * 4096) + (w << 11);  \
        const char* vg = (const char*)(vin + (size_t)(kt) * 4096) + (w << 11);  \
        char* lk = (char*)&KB[buf][0] + (w << 11);                              \
        char* lv = (char*)&VB[buf][0] + (w << 11);                              \
        const int l16 = lane << 4;                                              \
        gld16(kg + l16, lk); gld16(kg + 1024 + l16, lk + 1024);                 \
        gld16(vg + l16, lv); gld16(vg + 1024 + l16, lv + 1024);                 \
    }

    STAGE(0, 0)

    f4 O[2][4] = {};
    float mrun[2][4], lpart[2][4];
#pragma unroll
    for (int qf = 0; qf < 2; ++qf)
#pragma unroll
        for (int r = 0; r < 4; ++r) { mrun[qf][r] = -3.0e38f; lpart[qf][r] = 0.0f; }

    for (int kt = 0; kt < NSEQ / 64; ++kt) {
        const int p = kt & 1;
        __syncthreads();
        if (kt + 1 < NSEQ / 64) STAGE(kt + 1, p ^ 1)

        // ---- QK^T single-pass ----
        f4 s[2][4] = {};
#pragma unroll
        for (int kc = 0; kc < 2; ++kc)
#pragma unroll
            for (int nt = 0; nt < 4; ++nt) {
                const int key = (nt << 4) + li;
                const h8 bf = *reinterpret_cast<const h8*>(
                    &KB[p][(key << 6) + ((((kc << 2) + lb) ^ (key & 7)) << 3)]);
#pragma unroll
                for (int qf = 0; qf < 2; ++qf)
                    s[qf][nt] = __builtin_amdgcn_mfma_f32_16x16x32_f16(
                        qr[qf][kc], bf, s[qf][nt], 0, 0, 0);
            }

        // ---- softmax (exp2 domain; cheap defer check) ----
#pragma unroll
        for (int qf = 0; qf < 2; ++qf) {
            float lm[4];
#pragma unroll
            for (int r = 0; r < 4; ++r)
                lm[r] = fmaxf(fmaxf(s[qf][0][r], s[qf][1][r]),
                              fmaxf(s[qf][2][r], s[qf][3][r]));
            const int grow = (lm[0] > mrun[qf][0]) | (lm[1] > mrun[qf][1]) |
                             (lm[2] > mrun[qf][2]) | (lm[3] > mrun[qf][3]);
            if (__any(grow)) {
#pragma unroll
                for (int r = 0; r < 4; ++r) {
                    float m_ = lm[r];
#pragma unroll
                    for (int mk = 1; mk < 16; mk <<= 1)
                        m_ = fmaxf(m_, __shfl_xor(m_, mk));
                    const float mnew  = fmaxf(mrun[qf][r], m_);
                    const float alpha = exp2f(mrun[qf][r] - mnew);
                    mrun[qf][r] = mnew;
                    lpart[qf][r] *= alpha;
#pragma unroll
                    for (int nt = 0; nt < 4; ++nt) O[qf][nt][r] *= alpha;
                }
            }
#pragma unroll
            for (int nt = 0; nt < 4; ++nt) {
                const int key = (nt << 4) + li;
                const int cc = key >> 3, oo = key & 7;
#pragma unroll
                for (int r = 0; r < 4; ++r) {
                    const float pv = exp2f(s[qf][nt][r] - mrun[qf][r]);
                    lpart[qf][r] += pv;
                    const int row = (w << 5) + (qf << 4) + (lb << 2) + r;
                    P0[(row << 6) + ((cc ^ (row & 7)) << 3) + oo] = (_Float16)pv;
                }
            }
        }

        // ---- PV single-pass ----
#pragma unroll
        for (int kc = 0; kc < 2; ++kc) {
            h8 vB[4];
#pragma unroll
            for (int nt = 0; nt < 4; ++nt) {
                const int d = (nt << 4) + li;
                vB[nt] = *reinterpret_cast<const h8*>(
                    &VB[p][(d << 6) + ((((kc << 2) + lb) ^ (d & 7)) << 3)]);
            }
#pragma unroll
            for (int qf = 0; qf < 2; ++qf) {
                const int row = (w << 5) + (qf << 4) + li;
                const h8 pA = *reinterpret_cast<const h8*>(
                    &P0[(row << 6) + ((((kc << 2) + lb) ^ (row & 7)) << 3)]);
#pragma unroll
                for (int nt = 0; nt < 4; ++nt)
                    O[qf][nt] = __builtin_amdgcn_mfma_f32_16x16x32_f16(
                        pA, vB[nt], O[qf][nt], 0, 0, 0);
            }
        }
    }

    // ---- epilogue: normalize, write as out-GEMM A-image tile (mt, kt=h) ----
    const int mt_g = (bb * NSEQ + q0) >> 7;
    _Float16* aob = aoimg + ((size_t)mt_g * 8 + h) * 8192;
#pragma unroll
    for (int qf = 0; qf < 2; ++qf)
#pragma unroll
        for (int r = 0; r < 4; ++r) {
            float l = lpart[qf][r];
#pragma unroll
            for (int mk = 1; mk < 16; mk <<= 1) l += __shfl_xor(l, mk);
            const float inv = 1.0f / l;
            const int row = (w << 5) + (qf << 4) + (lb << 2) + r;
#pragma unroll
            for (int nt = 0; nt < 4; ++nt) {
                const int d = (nt << 4) + li;
                aob[(row << 6) + (((d >> 3) ^ (row & 7)) << 3) + (d & 7)] =
                    (_Float16)(O[qf][nt][r] * inv);
            }
        }
}

extern "C" void kernel_launch(void* const* d_in, const int* in_sizes, int n_in,
                              void* d_out, int out_size, void* d_ws, size_t ws_size,
                              hipStream_t stream) {
    const float* Q  = (const float*)d_in[0];
    const float* K  = (const float*)d_in[1];
    const float* V  = (const float*)d_in[2];
    const float* Wq = (const float*)d_in[3];
    const float* bq = (const float*)d_in[4];
    const float* Wk = (const float*)d_in[5];
    const float* bk = (const float*)d_in[6];
    const float* Wv = (const float*)d_in[7];
    const float* bv = (const float*)d_in[8];
    const float* Wo = (const float*)d_in[9];
    const float* bo = (const float*)d_in[10];
    float* out = (float*)d_out;
    char*  ws  = (char*)d_ws;

    _Float16* ximg = (_Float16*)(ws);                       // 25,165,824 B
    _Float16* wimg = (_Float16*)(ws + 25165824);            //  2,097,152 B
    _Float16* qimg = (_Float16*)(ws + 27262976);            //  8,388,608 B
    _Float16* kimg = (_Float16*)(ws + 35651584);            //  8,388,608 B
    _Float16* vimg = (_Float16*)(ws + 44040192);            //  8,388,608 B
    const size_t NEED = 52428800;
    // aoimg reuses ximg space (ximg dead after qkv_gemm)
    _Float16* aoimg = ximg;
    if (ws_size < NEED) {
        // tier-2: V image lives in d_out (dead before out_gemm writes Y)
        vimg = (_Float16*)d_out;
    }

    cvt_x_kernel<<<dim3(4096, 3), 256, 0, stream>>>(Q, K, V, ximg);
    cvt_w_kernel<<<dim3(256, 4), 256, 0, stream>>>(Wq, Wk, Wv, Wo, wimg);
    qkv_gemm_kernel<<<dim3(64, 8, 3), 256, 0, stream>>>(ximg, wimg, bq, bk, bv,
                                                        qimg, kimg, vimg);
    attn_mfma_kernel<<<dim3(512), 256, 0, stream>>>(qimg, kimg, vimg, aoimg);
    out_gemm_kernel<<<dim3(64, 8), 256, 0, stream>>>(aoimg, wimg, bo, out);
}